// Round 7
// baseline (878.684 us; speedup 1.0000x reference)
//
#include <hip/hip_runtime.h>
#include <hip/hip_bf16.h>
#include <math.h>

#define NND 6144
#define NED 12288
static constexpr float EPS_BN = 1e-5f;

// ---------------- ws layout (float offsets) ----------------
#define HN_OFF    0         // [N,32] Hn
#define HE_OFF    196608    // [N,2]
#define ST_OFF    208896    // [64]: sum0[16] sq0[16] | us5[5]
#define Y_OFF     208960    // YT [32,N]
#define T0_OFF    405568    // H [N,32], then Zc0 [E,16]
#define T1_OFF    602176    // ZtT [16,E]
#define Z0_OFF    798784    // [E]
#define Z1_OFF    811072    // [E]
#define U_OFF     823360    // [E]
#define S_OFF     835648    // [E]
#define PP_OFF    847936    // head partials [64][N]

typedef float floatx4 __attribute__((ext_vector_type(4)));

__device__ __forceinline__ float4 ntload4(const float* p) {
  floatx4 v = __builtin_nontemporal_load(reinterpret_cast<const floatx4*>(p));
  return make_float4(v.x, v.y, v.z, v.w);
}
__device__ __forceinline__ float4 ld4(const float* p) {
  return *reinterpret_cast<const float4*>(p);
}

__global__ void init_ws(float* __restrict__ p, int n) {
  int i = blockIdx.x * blockDim.x + threadIdx.x;
  if (i < n) p[i] = 0.f;
}

// CT[oc, m] = X[m,:] @ W[oc,:] (+bias). One thread per row m, transposed output.
template<int IC, int OC>
__global__ void small_mm_T(const float* __restrict__ X, const float* __restrict__ W,
                           const float* __restrict__ bias, float* __restrict__ CT, int M) {
  int m = blockIdx.x * blockDim.x + threadIdx.x;
  if (m >= M) return;
  float x[IC];
  #pragma unroll
  for (int k = 0; k < IC; k += 4) {
    float4 v = ld4(X + (size_t)m * IC + k);
    x[k] = v.x; x[k+1] = v.y; x[k+2] = v.z; x[k+3] = v.w;
  }
  #pragma unroll
  for (int oc = 0; oc < OC; ++oc) {
    float s = bias ? bias[oc] : 0.f;
    #pragma unroll
    for (int k = 0; k < IC; ++k) s = fmaf(x[k], W[oc * IC + k], s);
    CT[(size_t)oc * M + m] = s;
  }
}

// Barrier-free streaming GEMM: out[M,NC] = A[M,K] @ YT[NC,K]^T (+bias, relu).
// Each wave privately streams 3 rows of A (depth-1 prefetch); YT rows are
// L2-resident (<=786KB) and read per-wave. NO LDS staging, NO barriers in the
// hot loop -> loads stay in flight, no convoy stalls.
// Lane-partial accumulators reduced once at the end (fold + compact shuffle).
template<int NC, bool RELU, bool STATS>
__global__ __launch_bounds__(256)
void gemm_rows(const float* __restrict__ A, const float* __restrict__ YT,
               const float* __restrict__ bias, float* __restrict__ out,
               float* __restrict__ stats, int K) {
  const int lane = threadIdx.x & 63;
  const int w = threadIdx.x >> 6;
  const int rows0 = (blockIdx.x * 4 + w) * 3;   // wave owns rows0..rows0+2

  const float* ap[3];
  #pragma unroll
  for (int r = 0; r < 3; ++r) ap[r] = A + (size_t)(rows0 + r) * K;

  float acc[3][NC];
  #pragma unroll
  for (int r = 0; r < 3; ++r)
    #pragma unroll
    for (int c = 0; c < NC; ++c) acc[r][c] = 0.f;

  float4 a[3], an[3];
  #pragma unroll
  for (int r = 0; r < 3; ++r) a[r] = ld4(ap[r] + lane * 4);

  for (int kb = 0; kb < K; kb += 256) {
    const int k = kb + lane * 4;
    const bool more = (kb + 256) < K;
    if (more) {
      #pragma unroll
      for (int r = 0; r < 3; ++r) an[r] = ld4(ap[r] + k + 256);
    }
    #pragma unroll
    for (int c = 0; c < NC; ++c) {
      const float4 y = ld4(YT + (size_t)c * K + k);
      #pragma unroll
      for (int r = 0; r < 3; ++r) {
        acc[r][c] = fmaf(a[r].x, y.x, acc[r][c]);
        acc[r][c] = fmaf(a[r].y, y.y, acc[r][c]);
        acc[r][c] = fmaf(a[r].z, y.z, acc[r][c]);
        acc[r][c] = fmaf(a[r].w, y.w, acc[r][c]);
      }
    }
    if (more) {
      #pragma unroll
      for (int r = 0; r < 3; ++r) a[r] = an[r];
    }
  }

  // fold high lane bits so value class depends only on lane & (NC-1)
  #pragma unroll
  for (int r = 0; r < 3; ++r)
    #pragma unroll
    for (int c = 0; c < NC; ++c) {
      acc[r][c] += __shfl_xor(acc[r][c], 32, 64);
      if (NC == 16) acc[r][c] += __shfl_xor(acc[r][c], 16, 64);
    }

  // compact reduce per row: NC values over log2(NC) lane bits -> lane c holds sum c
  constexpr int LB = (NC == 16) ? 4 : 5;
  float rowv[3];
  #pragma unroll
  for (int r = 0; r < 3; ++r) {
    float wv[NC];
    #pragma unroll
    for (int c = 0; c < NC; ++c) wv[c] = acc[r][c];
    #pragma unroll
    for (int b = LB - 1; b >= 0; --b) {
      const int m = 1 << b;
      const bool hi = (lane & m) != 0;
      #pragma unroll
      for (int i = 0; i < (1 << b); ++i) {
        float x  = wv[i];
        float yy = wv[i + (1 << b)];
        float send = hi ? x : yy;
        float recv = __shfl_xor(send, m, 64);
        wv[i] = (hi ? yy : x) + recv;
      }
    }
    rowv[r] = wv[0];
  }

  const int csel = lane & (NC - 1);
  if (lane < NC) {
    #pragma unroll
    for (int r = 0; r < 3; ++r) {
      float v = rowv[r] + (bias ? bias[csel] : 0.f);
      if (RELU) v = fmaxf(v, 0.f);
      out[(size_t)(rows0 + r) * NC + csel] = v;
    }
  }

  if (STATS) {
    __shared__ float sst[32];
    if (threadIdx.x < 32) sst[threadIdx.x] = 0.f;
    __syncthreads();
    if (lane < 16) {
      const float v0 = rowv[0], v1 = rowv[1], v2 = rowv[2];
      atomicAdd(&sst[csel & 15], v0 + v1 + v2);
      atomicAdd(&sst[16 + (csel & 15)], v0 * v0 + v1 * v1 + v2 * v2);
    }
    __syncthreads();
    if (threadIdx.x < 32) atomicAdd(stats + threadIdx.x, sst[threadIdx.x]);
  }
}

// Row-dot pass, chunk 512, FULL depth-1 prefetch (matrix AND vectors).
// MODE 0: o1[row]=M·za, o2[row]=rowsum.  MODE 1: o1[2row]=M·za, o1[2row+1]=M·zb.
// REV: process rows in reverse order (consume L3-resident tail first).
template<int MODE, bool REV>
__global__ __launch_bounds__(256)
void rowpass(const float* __restrict__ Mt, const float* __restrict__ za,
             const float* __restrict__ zb, float* __restrict__ o1,
             float* __restrict__ o2, int K) {
  const int lane = threadIdx.x & 63;
  const int blk = REV ? (gridDim.x - 1 - blockIdx.x) : blockIdx.x;
  const int row = blk * 4 + (threadIdx.x >> 6);
  const float* mp = Mt + (size_t)row * K;
  float accA = 0.f, accB = 0.f;
  float4 a0 = ntload4(mp + lane * 4);
  float4 a1 = ntload4(mp + 256 + lane * 4);
  float4 z0 = ld4(za + lane * 4);
  float4 z1 = ld4(za + 256 + lane * 4);
  float4 y0, y1;
  if (MODE == 1) { y0 = ld4(zb + lane * 4); y1 = ld4(zb + 256 + lane * 4); }
  for (int kb = 0; kb < K; kb += 512) {
    const int k = kb + lane * 4;
    const bool more = (kb + 512) < K;
    float4 na0, na1, nz0, nz1, ny0, ny1;
    if (more) {
      na0 = ntload4(mp + k + 512);
      na1 = ntload4(mp + k + 768);
      nz0 = ld4(za + k + 512);
      nz1 = ld4(za + k + 768);
      if (MODE == 1) { ny0 = ld4(zb + k + 512); ny1 = ld4(zb + k + 768); }
    }
    if (MODE == 0) {
      accA += a0.x*z0.x + a0.y*z0.y + a0.z*z0.z + a0.w*z0.w
            + a1.x*z1.x + a1.y*z1.y + a1.z*z1.z + a1.w*z1.w;
      accB += a0.x + a0.y + a0.z + a0.w + a1.x + a1.y + a1.z + a1.w;
    } else {
      accA += a0.x*z0.x + a0.y*z0.y + a0.z*z0.z + a0.w*z0.w
            + a1.x*z1.x + a1.y*z1.y + a1.z*z1.z + a1.w*z1.w;
      accB += a0.x*y0.x + a0.y*y0.y + a0.z*y0.z + a0.w*y0.w
            + a1.x*y1.x + a1.y*y1.y + a1.z*y1.z + a1.w*y1.w;
    }
    if (more) {
      a0 = na0; a1 = na1; z0 = nz0; z1 = nz1;
      if (MODE == 1) { y0 = ny0; y1 = ny1; }
    }
  }
  #pragma unroll
  for (int m = 1; m < 64; m <<= 1) {
    accA += __shfl_xor(accA, m, 64);
    accB += __shfl_xor(accB, m, 64);
  }
  if (lane == 0) {
    if (MODE == 0) { o1[row] = accA; o2[row] = accB; }
    else { o1[row * 2] = accA; o1[row * 2 + 1] = accB; }
  }
}

// Z[e] = relu(max_c(g[c]*(x-m)*rsqrt(v+eps)+beta[c]))  -- layer-0 BN+max
__global__ void bn_max(const float* __restrict__ Zc, const float* __restrict__ stats,
                       const float* __restrict__ g, const float* __restrict__ beta,
                       float* __restrict__ Z, int E) {
  const int e = blockIdx.x * blockDim.x + threadIdx.x;
  if (e >= E) return;
  const float invE = 1.f / (float)E;
  float best = -3.4e38f;
  #pragma unroll
  for (int c = 0; c < 16; ++c) {
    float m = stats[c] * invE;
    float var = stats[16 + c] * invE - m * m;
    float sc = g[c] * rsqrtf(var + EPS_BN);
    float sh = beta[c] - m * sc;
    float x = Zc[(size_t)e * 16 + c];
    best = fmaxf(best, fmaf(x, sc, sh));
  }
  Z[e] = fmaxf(best, 0.f);
}

// Layer-1 collapsed BN stats: st5 = [Σu, Σs, Σu², Σs², Σus]
__global__ void us_stats(const float* __restrict__ u, const float* __restrict__ s,
                         float* __restrict__ st5) {
  const int e = blockIdx.x * 256 + threadIdx.x;
  const int lane = threadIdx.x & 63;
  const int w = threadIdx.x >> 6;
  const float uu = u[e], ss = s[e];
  float v[5] = {uu, ss, uu * uu, ss * ss, uu * ss};
  #pragma unroll
  for (int i = 0; i < 5; ++i)
    #pragma unroll
    for (int m = 1; m < 64; m <<= 1) v[i] += __shfl_xor(v[i], m, 64);
  __shared__ float red[4][5];
  if (lane == 0) {
    #pragma unroll
    for (int i = 0; i < 5; ++i) red[w][i] = v[i];
  }
  __syncthreads();
  if (threadIdx.x < 5) {
    float t = red[0][threadIdx.x] + red[1][threadIdx.x] + red[2][threadIdx.x] + red[3][threadIdx.x];
    atomicAdd(st5 + threadIdx.x, t);
  }
}

// Z1 directly from (u,s): Zc1[e,c] = W1[c]u + b1[c]s, BN via collapsed stats.
__global__ void z1_from_us(const float* __restrict__ u, const float* __restrict__ s,
                           const float* __restrict__ st5,
                           const float* __restrict__ W1, const float* __restrict__ b1,
                           const float* __restrict__ g, const float* __restrict__ beta,
                           float* __restrict__ Z1, int E) {
  const int e = blockIdx.x * blockDim.x + threadIdx.x;
  if (e >= E) return;
  const float invE = 1.f / (float)E;
  const float Su = st5[0], Ss = st5[1], Suu = st5[2], Sss = st5[3], Sus = st5[4];
  const float uu = u[e], ssv = s[e];
  float best = -3.4e38f;
  #pragma unroll
  for (int c = 0; c < 16; ++c) {
    const float wc = W1[c], bc = b1[c];
    const float mean = (wc * Su + bc * Ss) * invE;
    const float ex2 = (wc * wc * Suu + 2.f * wc * bc * Sus + bc * bc * Sss) * invE;
    const float var = ex2 - mean * mean;
    const float sc = g[c] * rsqrtf(var + EPS_BN);
    const float sh = beta[c] - mean * sc;
    best = fmaxf(best, fmaf(wc * uu + bc * ssv, sc, sh));
  }
  Z1[e] = fmaxf(best, 0.f);
}

// prepart[jb][n] = sum_{j in chunk jb} relu(Hcat[n]·fc1W[j] + fc1b[j]) * fc2W[j]
__global__ __launch_bounds__(256, 2)
void head(const float* __restrict__ Hn, const float* __restrict__ he,
          const float* __restrict__ W1, const float* __restrict__ b1,
          const float* __restrict__ w2, float* __restrict__ prepart) {
  const int t = threadIdx.x;
  const int nb = blockIdx.x;      // 8 blocks of 768 rows
  const int jb = blockIdx.y;      // 64 chunks of 192 j
  int n[3];
  float h[3][34];
  float acc[3] = {0.f, 0.f, 0.f};
  #pragma unroll
  for (int i = 0; i < 3; ++i) {
    n[i] = nb * 768 + i * 256 + t;
    #pragma unroll
    for (int k = 0; k < 32; k += 4) {
      float4 v = ld4(Hn + (size_t)n[i] * 32 + k);
      h[i][k] = v.x; h[i][k+1] = v.y; h[i][k+2] = v.z; h[i][k+3] = v.w;
    }
    float2 e2 = *reinterpret_cast<const float2*>(he + n[i] * 2);
    h[i][32] = e2.x;
    h[i][33] = e2.y;
  }
  const int j0 = jb * 192;
  for (int j = j0; j < j0 + 192; ++j) {
    const float* wp = W1 + (size_t)j * 34;
    const float bj = b1[j], vj = w2[j];
    float s0 = bj, s1 = bj, s2 = bj;
    #pragma unroll
    for (int k = 0; k < 34; ++k) {
      const float wk = wp[k];
      s0 = fmaf(h[0][k], wk, s0);
      s1 = fmaf(h[1][k], wk, s1);
      s2 = fmaf(h[2][k], wk, s2);
    }
    acc[0] += fmaxf(s0, 0.f) * vj;
    acc[1] += fmaxf(s1, 0.f) * vj;
    acc[2] += fmaxf(s2, 0.f) * vj;
  }
  #pragma unroll
  for (int i = 0; i < 3; ++i) prepart[(size_t)jb * NND + n[i]] = acc[i];
}

__global__ void final_k(const float* __restrict__ pp, const float* __restrict__ b2,
                        float* __restrict__ out, int Nn) {
  const int i = blockIdx.x * blockDim.x + threadIdx.x;
  if (i >= Nn) return;
  float s = 0.f;
  #pragma unroll
  for (int j = 0; j < 64; ++j) s += pp[(size_t)j * NND + i];
  out[i] = 1.f / (1.f + expf(-(s + b2[0])));
}

extern "C" void kernel_launch(void* const* d_in, const int* in_sizes, int n_in,
                              void* d_out, int out_size, void* d_ws, size_t ws_size,
                              hipStream_t stream) {
  const float* X_n   = (const float*)d_in[0];
  const float* X_e   = (const float*)d_in[1];
  const float* A     = (const float*)d_in[2];
  const float* L1    = (const float*)d_in[3];
  const float* B1    = (const float*)d_in[4];
  const float* gW0   = (const float*)d_in[5];
  const float* gb0   = (const float*)d_in[6];
  const float* gW1   = (const float*)d_in[7];
  const float* gb1   = (const float*)d_in[8];
  const float* tW0   = (const float*)d_in[9];
  const float* tb0   = (const float*)d_in[10];
  const float* bng0  = (const float*)d_in[11];
  const float* bnb0  = (const float*)d_in[12];
  const float* tW1   = (const float*)d_in[13];
  const float* tb1   = (const float*)d_in[14];
  const float* bng1  = (const float*)d_in[15];
  const float* bnb1  = (const float*)d_in[16];
  const float* fc1W  = (const float*)d_in[17];
  const float* fc1b  = (const float*)d_in[18];
  const float* fc2W  = (const float*)d_in[19];
  const float* fc2b  = (const float*)d_in[20];

  float* ws   = (float*)d_ws;
  float* Hn   = ws + HN_OFF;
  float* he   = ws + HE_OFF;
  float* st   = ws + ST_OFF;
  float* Y    = ws + Y_OFF;
  float* T0   = ws + T0_OFF;
  float* T1   = ws + T1_OFF;
  float* Z0   = ws + Z0_OFF;
  float* Z1   = ws + Z1_OFF;
  float* u    = ws + U_OFF;
  float* s    = ws + S_OFF;
  float* pp   = ws + PP_OFF;
  float* out  = (float*)d_out;

  // zero the atomic stats area (64 floats) every call
  init_ws<<<1, 64, 0, stream>>>(st, 64);

  // ---- GNN (barrier-free streaming gemm; A allocates L3 for 2nd pass) ----
  small_mm_T<32, 32><<<24, 256, 0, stream>>>(X_n, gW0, nullptr, Y, NND);          // Y0T
  gemm_rows<32, true, false><<<512, 256, 0, stream>>>(A, Y, gb0, T0, nullptr, NND);
  small_mm_T<32, 32><<<24, 256, 0, stream>>>(T0, gW1, nullptr, Y, NND);           // Y1T
  gemm_rows<32, true, false><<<512, 256, 0, stream>>>(A, Y, gb1, Hn, nullptr, NND);

  // ---- HoSC layer 0 (stats fused into epilogue) ----
  small_mm_T<16, 16><<<48, 256, 0, stream>>>(X_e, tW0, tb0, T1, NED);             // Zt0T
  gemm_rows<16, false, true><<<1024, 256, 0, stream>>>(L1, T1, nullptr, T0, st, NED);
  bn_max<<<48, 256, 0, stream>>>(T0, st, bng0, bnb0, Z0, NED);

  // ---- HoSC layer 1 (rank-1 collapse; REVERSE order: eat the L3 tail first) ----
  rowpass<0, true><<<3072, 256, 0, stream>>>(L1, Z0, nullptr, u, s, NED);
  us_stats<<<48, 256, 0, stream>>>(u, s, st + 32);
  z1_from_us<<<48, 256, 0, stream>>>(u, s, st + 32, tW1, tb1, bng1, bnb1, Z1, NED);

  // ---- H_e = B1 @ [Z0 Z1] ----
  rowpass<1, false><<<1536, 256, 0, stream>>>(B1, Z0, Z1, he, nullptr, NED);

  // ---- head (no atomics: per-jb partials, then reduce) ----
  head<<<dim3(8, 64), 256, 0, stream>>>(Hn, he, fc1W, fc1b, fc2W, pp);
  final_k<<<24, 256, 0, stream>>>(pp, fc2b, out, NND);
}

// Round 8
// 624.510 us; speedup vs baseline: 1.4070x; 1.4070x over previous
//
#include <hip/hip_runtime.h>
#include <hip/hip_bf16.h>
#include <math.h>

#define NND 6144
#define NED 12288
static constexpr float EPS_BN = 1e-5f;

// ---------------- ws layout (float offsets) ----------------
#define HN_OFF    0         // [N,32] Hn
#define HE_OFF    196608    // [N,2]
#define ST_OFF    208896    // [64]: sum0[16] sq0[16] | us5[5]
#define Y_OFF     208960    // YT [32,N]
#define T0_OFF    405568    // H [N,32], then Zc0 [E,16]
#define T1_OFF    602176    // ZtT [16,E]
#define Z0_OFF    798784    // [E]
#define Z1_OFF    811072    // [E]
#define U_OFF     823360    // [E]
#define S_OFF     835648    // [E]
#define PP_OFF    847936    // head partials [64][N]

typedef float floatx4 __attribute__((ext_vector_type(4)));

__device__ __forceinline__ float4 ntload4(const float* p) {
  floatx4 v = __builtin_nontemporal_load(reinterpret_cast<const floatx4*>(p));
  return make_float4(v.x, v.y, v.z, v.w);
}
__device__ __forceinline__ float4 ld4(const float* p) {
  return *reinterpret_cast<const float4*>(p);
}

// async global->LDS, 16 B per lane. LDS dest = wave-uniform base + lane*16.
__device__ __forceinline__ void gll16(const float* g, float* l) {
  __builtin_amdgcn_global_load_lds(
      (const __attribute__((address_space(1))) unsigned int*)g,
      (__attribute__((address_space(3))) unsigned int*)l, 16, 0, 0);
}

// CT[oc, m] = X[m,:] @ W[oc,:] (+bias). One thread per row m, transposed output.
// ZEROST: block 0 also zeroes the 64-float stats area (removes a launch).
template<int IC, int OC, bool ZEROST>
__global__ void small_mm_T(const float* __restrict__ X, const float* __restrict__ W,
                           const float* __restrict__ bias, float* __restrict__ CT,
                           float* __restrict__ zst, int M) {
  if (ZEROST && blockIdx.x == 0 && threadIdx.x < 64) zst[threadIdx.x] = 0.f;
  int m = blockIdx.x * blockDim.x + threadIdx.x;
  if (m >= M) return;
  float x[IC];
  #pragma unroll
  for (int k = 0; k < IC; k += 4) {
    float4 v = ld4(X + (size_t)m * IC + k);
    x[k] = v.x; x[k+1] = v.y; x[k+2] = v.z; x[k+3] = v.w;
  }
  #pragma unroll
  for (int oc = 0; oc < OC; ++oc) {
    float s = bias ? bias[oc] : 0.f;
    #pragma unroll
    for (int k = 0; k < IC; ++k) s = fmaf(x[k], W[oc * IC + k], s);
    CT[(size_t)oc * M + m] = s;
  }
}

// out[M,NC] = A[M,K] @ YT[NC,K]^T. Chunk 512, Y staged via global_load_lds
// (block-shared, linear layout), A reg-double-buffered. 2 barriers per chunk.
// block=256 (4 waves). CG col-groups of 16; ROWS=(4/CG)*4 rows per block.
template<int NC, int CG, bool RELU, bool STATS>
__global__ __launch_bounds__(256)
void gemm_g(const float* __restrict__ A, const float* __restrict__ YT,
            const float* __restrict__ bias, float* __restrict__ out,
            float* __restrict__ stats, int K) {
  constexpr int ROWS = (4 / CG) * 4;
  constexpr int GPW = NC * 2 / 4;   // gll16 ops per wave per chunk (1KB each)
  __shared__ float Yb[NC][512];

  const int tid = threadIdx.x;
  const int lane = tid & 63;
  const int w = tid >> 6;
  const int cg = w % CG, rg = w / CG;
  const int r0 = blockIdx.x * ROWS;
  const int c0 = cg * 16;

  const float* ap[4];
  #pragma unroll
  for (int r = 0; r < 4; ++r) ap[r] = A + (size_t)(r0 + rg * 4 + r) * K;

  auto stage = [&](int kb) {
    #pragma unroll
    for (int i = 0; i < GPW; ++i) {
      const int f = w * GPW + i;
      const int row = f >> 1, half = f & 1;
      gll16(YT + (size_t)row * K + kb + half * 256 + lane * 4,
            &Yb[row][half * 256]);
    }
  };

  float4 av[4][2], av2[4][2];
  auto loadA = [&](int kb, float4 (*dst)[2]) {
    #pragma unroll
    for (int r = 0; r < 4; ++r)
      #pragma unroll
      for (int s = 0; s < 2; ++s)
        dst[r][s] = ld4(ap[r] + kb + s * 256 + lane * 4);
  };

  float acc[4][16];
  #pragma unroll
  for (int r = 0; r < 4; ++r)
    #pragma unroll
    for (int c = 0; c < 16; ++c) acc[r][c] = 0.f;

  stage(0);
  loadA(0, av);
  __syncthreads();                       // chunk 0 in LDS + regs

  for (int kb = 0; kb < K; kb += 512) {
    #pragma unroll
    for (int s = 0; s < 2; ++s)
      #pragma unroll
      for (int c = 0; c < 16; ++c) {
        const float4 y = *reinterpret_cast<const float4*>(&Yb[c0 + c][s * 256 + lane * 4]);
        #pragma unroll
        for (int r = 0; r < 4; ++r) {
          acc[r][c] = fmaf(av[r][s].x, y.x, acc[r][c]);
          acc[r][c] = fmaf(av[r][s].y, y.y, acc[r][c]);
          acc[r][c] = fmaf(av[r][s].z, y.z, acc[r][c]);
          acc[r][c] = fmaf(av[r][s].w, y.w, acc[r][c]);
        }
      }
    const bool more = (kb + 512) < K;
    __syncthreads();                     // all waves done reading Yb
    if (more) {
      stage(kb + 512);                   // gll direct to Yb
      loadA(kb + 512, av2);
      __syncthreads();                   // chunk kb+512 complete & visible
      #pragma unroll
      for (int r = 0; r < 4; ++r) {
        av[r][0] = av2[r][0];
        av[r][1] = av2[r][1];
      }
    }
  }

  // Compact cross-lane reduce: 64 values x 64 lanes -> lane l holds value l.
  float wv[64];
  #pragma unroll
  for (int r = 0; r < 4; ++r)
    #pragma unroll
    for (int c = 0; c < 16; ++c) wv[r * 16 + c] = acc[r][c];
  #pragma unroll
  for (int b = 5; b >= 0; --b) {
    const int m = 1 << b;
    const bool hi = (lane & m) != 0;
    #pragma unroll
    for (int i = 0; i < (1 << b); ++i) {
      float a  = wv[i];
      float bb = wv[i + (1 << b)];
      float send = hi ? a : bb;
      float recv = __shfl_xor(send, m, 64);
      wv[i] = (hi ? bb : a) + recv;
    }
  }

  const int rsel = lane >> 4, csel = lane & 15;
  float v = wv[0] + (bias ? bias[c0 + csel] : 0.f);
  if (RELU) v = fmaxf(v, 0.f);
  out[(size_t)(r0 + rg * 4 + rsel) * NC + c0 + csel] = v;

  if (STATS) {
    __shared__ float sst[32];
    if (tid < 32) sst[tid] = 0.f;
    __syncthreads();
    float sv = v, qv = v * v;
    sv += __shfl_xor(sv, 16, 64); sv += __shfl_xor(sv, 32, 64);
    qv += __shfl_xor(qv, 16, 64); qv += __shfl_xor(qv, 32, 64);
    if (lane < 16) { atomicAdd(&sst[csel], sv); atomicAdd(&sst[16 + csel], qv); }
    __syncthreads();
    if (tid < 32) atomicAdd(stats + tid, sst[tid]);
  }
}

// Row-dot pass: 2 rows per wave (8 per block), chunk 512, full depth-1 prefetch.
// MODE 0: o1[row]=M·za, o2[row]=rowsum; fused st5 = [Σu,Σs,Σu²,Σs²,Σus] atomics.
// MODE 1: o1[2row]=M·za, o1[2row+1]=M·zb.
// REV: reverse block order (consume L3-resident tail of M first).
template<int MODE, bool REV>
__global__ __launch_bounds__(256)
void rowpass2(const float* __restrict__ Mt, const float* __restrict__ za,
              const float* __restrict__ zb, float* __restrict__ o1,
              float* __restrict__ o2, float* __restrict__ st5, int K) {
  const int lane = threadIdx.x & 63;
  const int w = threadIdx.x >> 6;
  const int blk = REV ? (gridDim.x - 1 - blockIdx.x) : blockIdx.x;
  const int rA = blk * 8 + w * 2;
  const float* mpA = Mt + (size_t)rA * K;
  const float* mpB = mpA + K;
  float uA = 0.f, vA = 0.f, uB = 0.f, vB = 0.f;

  float4 a0A = ntload4(mpA + lane * 4), a1A = ntload4(mpA + 256 + lane * 4);
  float4 a0B = ntload4(mpB + lane * 4), a1B = ntload4(mpB + 256 + lane * 4);
  float4 z0 = ld4(za + lane * 4), z1 = ld4(za + 256 + lane * 4);
  float4 y0, y1;
  if (MODE == 1) { y0 = ld4(zb + lane * 4); y1 = ld4(zb + 256 + lane * 4); }

  for (int kb = 0; kb < K; kb += 512) {
    const int k = kb + lane * 4;
    const bool more = (kb + 512) < K;
    float4 n0A, n1A, n0B, n1B, nz0, nz1, ny0, ny1;
    if (more) {
      n0A = ntload4(mpA + k + 512); n1A = ntload4(mpA + k + 768);
      n0B = ntload4(mpB + k + 512); n1B = ntload4(mpB + k + 768);
      nz0 = ld4(za + k + 512);      nz1 = ld4(za + k + 768);
      if (MODE == 1) { ny0 = ld4(zb + k + 512); ny1 = ld4(zb + k + 768); }
    }
    uA += a0A.x*z0.x + a0A.y*z0.y + a0A.z*z0.z + a0A.w*z0.w
        + a1A.x*z1.x + a1A.y*z1.y + a1A.z*z1.z + a1A.w*z1.w;
    uB += a0B.x*z0.x + a0B.y*z0.y + a0B.z*z0.z + a0B.w*z0.w
        + a1B.x*z1.x + a1B.y*z1.y + a1B.z*z1.z + a1B.w*z1.w;
    if (MODE == 0) {
      vA += a0A.x + a0A.y + a0A.z + a0A.w + a1A.x + a1A.y + a1A.z + a1A.w;
      vB += a0B.x + a0B.y + a0B.z + a0B.w + a1B.x + a1B.y + a1B.z + a1B.w;
    } else {
      vA += a0A.x*y0.x + a0A.y*y0.y + a0A.z*y0.z + a0A.w*y0.w
          + a1A.x*y1.x + a1A.y*y1.y + a1A.z*y1.z + a1A.w*y1.w;
      vB += a0B.x*y0.x + a0B.y*y0.y + a0B.z*y0.z + a0B.w*y0.w
          + a1B.x*y1.x + a1B.y*y1.y + a1B.z*y1.z + a1B.w*y1.w;
    }
    if (more) {
      a0A = n0A; a1A = n1A; a0B = n0B; a1B = n1B; z0 = nz0; z1 = nz1;
      if (MODE == 1) { y0 = ny0; y1 = ny1; }
    }
  }
  #pragma unroll
  for (int m = 1; m < 64; m <<= 1) {
    uA += __shfl_xor(uA, m, 64); vA += __shfl_xor(vA, m, 64);
    uB += __shfl_xor(uB, m, 64); vB += __shfl_xor(vB, m, 64);
  }
  if (lane == 0) {
    if (MODE == 0) {
      o1[rA] = uA; o2[rA] = vA;
      o1[rA + 1] = uB; o2[rA + 1] = vB;
    } else {
      o1[rA * 2] = uA;     o1[rA * 2 + 1] = vA;
      o1[rA * 2 + 2] = uB; o1[rA * 2 + 3] = vB;
    }
  }
  if (MODE == 0) {
    __shared__ float red[4][5];
    if (lane == 0) {
      red[w][0] = uA + uB;
      red[w][1] = vA + vB;
      red[w][2] = uA * uA + uB * uB;
      red[w][3] = vA * vA + vB * vB;
      red[w][4] = uA * vA + uB * vB;
    }
    __syncthreads();
    if (threadIdx.x < 5) {
      float t = red[0][threadIdx.x] + red[1][threadIdx.x]
              + red[2][threadIdx.x] + red[3][threadIdx.x];
      atomicAdd(st5 + threadIdx.x, t);
    }
  }
}

// Z[e] = relu(max_c(g[c]*(x-m)*rsqrt(v+eps)+beta[c]))  -- layer-0 BN+max
__global__ void bn_max(const float* __restrict__ Zc, const float* __restrict__ stats,
                       const float* __restrict__ g, const float* __restrict__ beta,
                       float* __restrict__ Z, int E) {
  const int e = blockIdx.x * blockDim.x + threadIdx.x;
  if (e >= E) return;
  const float invE = 1.f / (float)E;
  float best = -3.4e38f;
  #pragma unroll
  for (int c = 0; c < 16; ++c) {
    float m = stats[c] * invE;
    float var = stats[16 + c] * invE - m * m;
    float sc = g[c] * rsqrtf(var + EPS_BN);
    float sh = beta[c] - m * sc;
    float x = Zc[(size_t)e * 16 + c];
    best = fmaxf(best, fmaf(x, sc, sh));
  }
  Z[e] = fmaxf(best, 0.f);
}

// Z1 directly from (u,s): Zc1[e,c] = W1[c]u + b1[c]s, BN via collapsed stats.
__global__ void z1_from_us(const float* __restrict__ u, const float* __restrict__ s,
                           const float* __restrict__ st5,
                           const float* __restrict__ W1, const float* __restrict__ b1,
                           const float* __restrict__ g, const float* __restrict__ beta,
                           float* __restrict__ Z1, int E) {
  const int e = blockIdx.x * blockDim.x + threadIdx.x;
  if (e >= E) return;
  const float invE = 1.f / (float)E;
  const float Su = st5[0], Ss = st5[1], Suu = st5[2], Sss = st5[3], Sus = st5[4];
  const float uu = u[e], ssv = s[e];
  float best = -3.4e38f;
  #pragma unroll
  for (int c = 0; c < 16; ++c) {
    const float wc = W1[c], bc = b1[c];
    const float mean = (wc * Su + bc * Ss) * invE;
    const float ex2 = (wc * wc * Suu + 2.f * wc * bc * Sus + bc * bc * Sss) * invE;
    const float var = ex2 - mean * mean;
    const float sc = g[c] * rsqrtf(var + EPS_BN);
    const float sh = beta[c] - mean * sc;
    best = fmaxf(best, fmaf(wc * uu + bc * ssv, sc, sh));
  }
  Z1[e] = fmaxf(best, 0.f);
}

// prepart[jb][n] = sum_{j in chunk jb} relu(Hcat[n]·fc1W[j] + fc1b[j]) * fc2W[j]
__global__ __launch_bounds__(256, 2)
void head(const float* __restrict__ Hn, const float* __restrict__ he,
          const float* __restrict__ W1, const float* __restrict__ b1,
          const float* __restrict__ w2, float* __restrict__ prepart) {
  const int t = threadIdx.x;
  const int nb = blockIdx.x;      // 8 blocks of 768 rows
  const int jb = blockIdx.y;      // 64 chunks of 192 j
  int n[3];
  float h[3][34];
  float acc[3] = {0.f, 0.f, 0.f};
  #pragma unroll
  for (int i = 0; i < 3; ++i) {
    n[i] = nb * 768 + i * 256 + t;
    #pragma unroll
    for (int k = 0; k < 32; k += 4) {
      float4 v = ld4(Hn + (size_t)n[i] * 32 + k);
      h[i][k] = v.x; h[i][k+1] = v.y; h[i][k+2] = v.z; h[i][k+3] = v.w;
    }
    float2 e2 = *reinterpret_cast<const float2*>(he + n[i] * 2);
    h[i][32] = e2.x;
    h[i][33] = e2.y;
  }
  const int j0 = jb * 192;
  for (int j = j0; j < j0 + 192; ++j) {
    const float* wp = W1 + (size_t)j * 34;
    const float bj = b1[j], vj = w2[j];
    float s0 = bj, s1 = bj, s2 = bj;
    #pragma unroll
    for (int k = 0; k < 34; ++k) {
      const float wk = wp[k];
      s0 = fmaf(h[0][k], wk, s0);
      s1 = fmaf(h[1][k], wk, s1);
      s2 = fmaf(h[2][k], wk, s2);
    }
    acc[0] += fmaxf(s0, 0.f) * vj;
    acc[1] += fmaxf(s1, 0.f) * vj;
    acc[2] += fmaxf(s2, 0.f) * vj;
  }
  #pragma unroll
  for (int i = 0; i < 3; ++i) prepart[(size_t)jb * NND + n[i]] = acc[i];
}

__global__ void final_k(const float* __restrict__ pp, const float* __restrict__ b2,
                        float* __restrict__ out, int Nn) {
  const int i = blockIdx.x * blockDim.x + threadIdx.x;
  if (i >= Nn) return;
  float s = 0.f;
  #pragma unroll
  for (int j = 0; j < 64; ++j) s += pp[(size_t)j * NND + i];
  out[i] = 1.f / (1.f + expf(-(s + b2[0])));
}

extern "C" void kernel_launch(void* const* d_in, const int* in_sizes, int n_in,
                              void* d_out, int out_size, void* d_ws, size_t ws_size,
                              hipStream_t stream) {
  const float* X_n   = (const float*)d_in[0];
  const float* X_e   = (const float*)d_in[1];
  const float* A     = (const float*)d_in[2];
  const float* L1    = (const float*)d_in[3];
  const float* B1    = (const float*)d_in[4];
  const float* gW0   = (const float*)d_in[5];
  const float* gb0   = (const float*)d_in[6];
  const float* gW1   = (const float*)d_in[7];
  const float* gb1   = (const float*)d_in[8];
  const float* tW0   = (const float*)d_in[9];
  const float* tb0   = (const float*)d_in[10];
  const float* bng0  = (const float*)d_in[11];
  const float* bnb0  = (const float*)d_in[12];
  const float* tW1   = (const float*)d_in[13];
  const float* tb1   = (const float*)d_in[14];
  const float* bng1  = (const float*)d_in[15];
  const float* bnb1  = (const float*)d_in[16];
  const float* fc1W  = (const float*)d_in[17];
  const float* fc1b  = (const float*)d_in[18];
  const float* fc2W  = (const float*)d_in[19];
  const float* fc2b  = (const float*)d_in[20];

  float* ws   = (float*)d_ws;
  float* Hn   = ws + HN_OFF;
  float* he   = ws + HE_OFF;
  float* st   = ws + ST_OFF;
  float* Y    = ws + Y_OFF;
  float* T0   = ws + T0_OFF;
  float* T1   = ws + T1_OFF;
  float* Z0   = ws + Z0_OFF;
  float* Z1   = ws + Z1_OFF;
  float* u    = ws + U_OFF;
  float* s    = ws + S_OFF;
  float* pp   = ws + PP_OFF;
  float* out  = (float*)d_out;

  // ---- GNN (A cacheable: 2nd pass hits L3) ----
  small_mm_T<32, 32, false><<<24, 256, 0, stream>>>(X_n, gW0, nullptr, Y, nullptr, NND);
  gemm_g<32, 2, true, false><<<768, 256, 0, stream>>>(A, Y, gb0, T0, nullptr, NND);
  small_mm_T<32, 32, false><<<24, 256, 0, stream>>>(T0, gW1, nullptr, Y, nullptr, NND);
  gemm_g<32, 2, true, false><<<768, 256, 0, stream>>>(A, Y, gb1, Hn, nullptr, NND);

  // ---- HoSC layer 0 (stats zeroed by small_mm_T, accumulated in gemm epilogue) ----
  small_mm_T<16, 16, true><<<48, 256, 0, stream>>>(X_e, tW0, tb0, T1, st, NED);
  gemm_g<16, 1, false, true><<<768, 256, 0, stream>>>(L1, T1, nullptr, T0, st, NED);
  bn_max<<<48, 256, 0, stream>>>(T0, st, bng0, bnb0, Z0, NED);

  // ---- HoSC layer 1 (rank-1 collapse; st5 fused into rowpass epilogue) ----
  rowpass2<0, true><<<1536, 256, 0, stream>>>(L1, Z0, nullptr, u, s, st + 32, NED);
  z1_from_us<<<48, 256, 0, stream>>>(u, s, st + 32, tW1, tb1, bng1, bnb1, Z1, NED);

  // ---- H_e = B1 @ [Z0 Z1] ----
  rowpass2<1, false><<<768, 256, 0, stream>>>(B1, Z0, Z1, he, nullptr, nullptr, NED);

  // ---- head (no atomics: per-jb partials, then reduce) ----
  head<<<dim3(8, 64), 256, 0, stream>>>(Hn, he, fc1W, fc1b, fc2W, pp);
  final_k<<<24, 256, 0, stream>>>(pp, fc2b, out, NND);
}

// Round 10
// 610.325 us; speedup vs baseline: 1.4397x; 1.0232x over previous
//
#include <hip/hip_runtime.h>
#include <hip/hip_cooperative_groups.h>
#include <math.h>

namespace cg = cooperative_groups;

#define NND 6144
#define NED 12288
#define GRID 512
static constexpr float EPS_BN = 1e-5f;

// ---------------- ws layout (float offsets) ----------------
#define HN_OFF    0         // Hn [N,32]
#define HE_OFF    196608    // he [N,2]
#define ST_OFF    208896    // [64]: sum0[16] sq0[16] | us5[5]
#define Y_OFF     208960    // YT [32,N]
#define T0_OFF    405568    // H [N,32] / Zc0 [E,16]
#define T1_OFF    602176    // ZtT [16,E]
#define Z0_OFF    798784    // [E]
#define Z1_OFF    811072    // [E]
#define U_OFF     823360    // [E]
#define S_OFF     835648    // [E]
#define PP_OFF    847936    // head partials [64][N]

typedef float floatx4 __attribute__((ext_vector_type(4)));

__device__ __forceinline__ float4 ntload4(const float* p) {
  floatx4 v = __builtin_nontemporal_load(reinterpret_cast<const floatx4*>(p));
  return make_float4(v.x, v.y, v.z, v.w);
}
__device__ __forceinline__ float4 ld4(const float* p) {
  return *reinterpret_cast<const float4*>(p);
}
__device__ __forceinline__ void gll16(const float* g, float* l) {
  __builtin_amdgcn_global_load_lds(
      (const __attribute__((address_space(1))) unsigned int*)g,
      (__attribute__((address_space(3))) unsigned int*)l, 16, 0, 0);
}

struct Params {
  const float *X_n, *X_e, *A, *L1, *B1;
  const float *gW0, *gb0, *gW1, *gb1;
  const float *tW0, *tb0, *bng0, *bnb0;
  const float *tW1, *tb1, *bng1, *bnb1;
  const float *fc1W, *fc1b, *fc2W, *fc2b;
  float *ws;
  float *out;
};

// PHASE == 0: full pipeline with grid.sync (cooperative launch).
// PHASE == k (1..11): only phase k (fallback, one kernel per phase).
template<int PHASE>
__global__ __launch_bounds__(256, 2) void pipeline(Params p) {
  __shared__ float lds[12288];              // 48 KB pool (2 blocks/CU)
  float* sst = &lds[12032];
  float* red = &lds[12064];

  const int tid  = threadIdx.x;
  const int lane = tid & 63;
  const int w    = tid >> 6;
  const int blk  = blockIdx.x;
  const int gtid = blk * 256 + tid;
  constexpr bool ALL = (PHASE == 0);

  float* Hn = p.ws + HN_OFF;
  float* he = p.ws + HE_OFF;
  float* st = p.ws + ST_OFF;
  float* Y  = p.ws + Y_OFF;
  float* T0 = p.ws + T0_OFF;
  float* T1 = p.ws + T1_OFF;
  float* Z0 = p.ws + Z0_OFF;
  float* Z1 = p.ws + Z1_OFF;
  float* u  = p.ws + U_OFF;
  float* s  = p.ws + S_OFF;
  float* pp = p.ws + PP_OFF;

  // gemm32: out = relu(A@Y^T + b). 12 rows/block, 4 waves x 3 rows x 32 cols.
  // LDS: Y 32x256 (lds[0..8191]) + A 12x256 (lds[8192..11263]).
  auto gemm32 = [&](const float* bias, float* outp) {
    const int r0 = blk * 12;
    float acc[3][32];
    #pragma unroll
    for (int r = 0; r < 3; ++r)
      #pragma unroll
      for (int c = 0; c < 32; ++c) acc[r][c] = 0.f;

    for (int kb = 0; kb < NND; kb += 256) {
      #pragma unroll
      for (int i = 0; i < 8; ++i) {
        const int yr = w * 8 + i;
        gll16(Y + (size_t)yr * NND + kb + lane * 4, &lds[yr * 256]);
      }
      #pragma unroll
      for (int i = 0; i < 3; ++i) {
        const int ar = w * 3 + i;
        gll16(p.A + (size_t)(r0 + ar) * NND + kb + lane * 4, &lds[8192 + ar * 256]);
      }
      __syncthreads();
      float4 av[3];
      #pragma unroll
      for (int r = 0; r < 3; ++r)
        av[r] = ld4(&lds[8192 + (w * 3 + r) * 256 + lane * 4]);
      #pragma unroll
      for (int c = 0; c < 32; ++c) {
        const float4 y = ld4(&lds[c * 256 + lane * 4]);
        #pragma unroll
        for (int r = 0; r < 3; ++r) {
          acc[r][c] = fmaf(av[r].x, y.x, acc[r][c]);
          acc[r][c] = fmaf(av[r].y, y.y, acc[r][c]);
          acc[r][c] = fmaf(av[r].z, y.z, acc[r][c]);
          acc[r][c] = fmaf(av[r].w, y.w, acc[r][c]);
        }
      }
      __syncthreads();
    }
    // per-row reduce: fold lane-bit 5, compact 5 bits -> lane c holds col c
    #pragma unroll
    for (int r = 0; r < 3; ++r) {
      float wv[32];
      #pragma unroll
      for (int c = 0; c < 32; ++c)
        wv[c] = acc[r][c] + __shfl_xor(acc[r][c], 32, 64);
      #pragma unroll
      for (int b = 4; b >= 0; --b) {
        const int m = 1 << b;
        const bool hi = (lane & m) != 0;
        #pragma unroll
        for (int i = 0; i < (1 << b); ++i) {
          float x = wv[i], yv = wv[i + (1 << b)];
          float send = hi ? x : yv;
          float recv = __shfl_xor(send, m, 64);
          wv[i] = (hi ? yv : x) + recv;
        }
      }
      if (lane < 32) {
        float v = fmaxf(wv[0] + bias[lane], 0.f);
        outp[(size_t)(r0 + w * 3 + r) * 32 + lane] = v;
      }
    }
  };

  // ---- P1: zero stats; Y0T = X_n@gW0^T; ZtT = X_e@tW0^T + tb0 ----
  if constexpr (ALL || PHASE == 1) {
    if (blk == 0 && tid < 64) st[tid] = 0.f;
    if (gtid < NND) {
      const int m = gtid;
      float x[32];
      #pragma unroll
      for (int k = 0; k < 32; k += 4) {
        float4 v = ld4(p.X_n + (size_t)m * 32 + k);
        x[k] = v.x; x[k+1] = v.y; x[k+2] = v.z; x[k+3] = v.w;
      }
      #pragma unroll
      for (int oc = 0; oc < 32; ++oc) {
        float acc = 0.f;
        #pragma unroll
        for (int k = 0; k < 32; ++k) acc = fmaf(x[k], p.gW0[oc * 32 + k], acc);
        Y[(size_t)oc * NND + m] = acc;
      }
    } else if (gtid < NND + NED) {
      const int e = gtid - NND;
      float x[16];
      #pragma unroll
      for (int k = 0; k < 16; k += 4) {
        float4 v = ld4(p.X_e + (size_t)e * 16 + k);
        x[k] = v.x; x[k+1] = v.y; x[k+2] = v.z; x[k+3] = v.w;
      }
      #pragma unroll
      for (int oc = 0; oc < 16; ++oc) {
        float acc = p.tb0[oc];
        #pragma unroll
        for (int k = 0; k < 16; ++k) acc = fmaf(x[k], p.tW0[oc * 16 + k], acc);
        T1[(size_t)oc * NED + e] = acc;
      }
    }
  }
  if constexpr (ALL) cg::this_grid().sync();

  // ---- P2: H(T0) = relu(A@Y0 + gb0) ----
  if constexpr (ALL || PHASE == 2) gemm32(p.gb0, T0);
  if constexpr (ALL) cg::this_grid().sync();

  // ---- P3: Y1T = H@gW1^T ----
  if constexpr (ALL || PHASE == 3) {
    if (gtid < NND) {
      const int m = gtid;
      float x[32];
      #pragma unroll
      for (int k = 0; k < 32; k += 4) {
        float4 v = ld4(T0 + (size_t)m * 32 + k);
        x[k] = v.x; x[k+1] = v.y; x[k+2] = v.z; x[k+3] = v.w;
      }
      #pragma unroll
      for (int oc = 0; oc < 32; ++oc) {
        float acc = 0.f;
        #pragma unroll
        for (int k = 0; k < 32; ++k) acc = fmaf(x[k], p.gW1[oc * 32 + k], acc);
        Y[(size_t)oc * NND + m] = acc;
      }
    }
  }
  if constexpr (ALL) cg::this_grid().sync();

  // ---- P4: Hn = relu(A@Y1 + gb1) ----
  if constexpr (ALL || PHASE == 4) gemm32(p.gb1, Hn);
  if constexpr (ALL) cg::this_grid().sync();

  // ---- P5: Zc0(T0) = L1@ZtT^T + fused BN stats ----
  // 24 rows/block, 4 waves x 6 rows x 16 cols.
  // LDS: Zt 16x256 (lds[0..4095]) + L1 24x256 (lds[4096..10239]).
  if constexpr (ALL || PHASE == 5) {
    const int r0 = blk * 24;
    float acc[6][16];
    #pragma unroll
    for (int r = 0; r < 6; ++r)
      #pragma unroll
      for (int c = 0; c < 16; ++c) acc[r][c] = 0.f;

    for (int kb = 0; kb < NED; kb += 256) {
      #pragma unroll
      for (int i = 0; i < 4; ++i) {
        const int yr = w * 4 + i;
        gll16(T1 + (size_t)yr * NED + kb + lane * 4, &lds[yr * 256]);
      }
      #pragma unroll
      for (int i = 0; i < 6; ++i) {
        const int ar = w * 6 + i;
        gll16(p.L1 + (size_t)(r0 + ar) * NED + kb + lane * 4, &lds[4096 + ar * 256]);
      }
      __syncthreads();
      float4 av[6];
      #pragma unroll
      for (int r = 0; r < 6; ++r)
        av[r] = ld4(&lds[4096 + (w * 6 + r) * 256 + lane * 4]);
      #pragma unroll
      for (int c = 0; c < 16; ++c) {
        const float4 y = ld4(&lds[c * 256 + lane * 4]);
        #pragma unroll
        for (int r = 0; r < 6; ++r) {
          acc[r][c] = fmaf(av[r].x, y.x, acc[r][c]);
          acc[r][c] = fmaf(av[r].y, y.y, acc[r][c]);
          acc[r][c] = fmaf(av[r].z, y.z, acc[r][c]);
          acc[r][c] = fmaf(av[r].w, y.w, acc[r][c]);
        }
      }
      __syncthreads();
    }
    // reduce in 3 row-pairs: 32 values (2 rows x 16 cols) per pass
    float stS = 0.f, stQ = 0.f;
    #pragma unroll
    for (int pr = 0; pr < 3; ++pr) {
      float wv[32];
      #pragma unroll
      for (int c = 0; c < 16; ++c) {
        wv[c]      = acc[2*pr][c]   + __shfl_xor(acc[2*pr][c], 32, 64);
        wv[16 + c] = acc[2*pr+1][c] + __shfl_xor(acc[2*pr+1][c], 32, 64);
      }
      #pragma unroll
      for (int b = 4; b >= 0; --b) {
        const int m = 1 << b;
        const bool hi = (lane & m) != 0;
        #pragma unroll
        for (int i = 0; i < (1 << b); ++i) {
          float x = wv[i], yv = wv[i + (1 << b)];
          float send = hi ? x : yv;
          float recv = __shfl_xor(send, m, 64);
          wv[i] = (hi ? yv : x) + recv;
        }
      }
      if (lane < 32) {
        const int rsel = lane >> 4, csel = lane & 15;
        const float v = wv[0];
        T0[(size_t)(r0 + w * 6 + pr * 2 + rsel) * 16 + csel] = v;
        stS += v; stQ += v * v;
      }
    }
    if (tid < 32) sst[tid] = 0.f;
    __syncthreads();
    if (lane < 32) {
      atomicAdd(&sst[lane & 15], stS);
      atomicAdd(&sst[16 + (lane & 15)], stQ);
    }
    __syncthreads();
    if (tid < 32) atomicAdd(st + tid, sst[tid]);
  }
  if constexpr (ALL) cg::this_grid().sync();

  // ---- P6: Z0 = relu(max_c BN(Zc0)) ----
  if constexpr (ALL || PHASE == 6) {
    if (gtid < NED) {
      const int e = gtid;
      const float invE = 1.f / (float)NED;
      float best = -3.4e38f;
      #pragma unroll
      for (int c = 0; c < 16; ++c) {
        float m = st[c] * invE;
        float var = st[16 + c] * invE - m * m;
        float sc = p.bng0[c] * rsqrtf(var + EPS_BN);
        float sh = p.bnb0[c] - m * sc;
        best = fmaxf(best, fmaf(T0[(size_t)e * 16 + c], sc, sh));
      }
      Z0[e] = fmaxf(best, 0.f);
    }
  }
  if constexpr (ALL) cg::this_grid().sync();

  // ---- P7: u = L1@Z0, s = L1@1, fused st5. REV order (L3 tail reuse). ----
  if constexpr (ALL || PHASE == 7) {
    const int rb = GRID - 1 - blk;
    const int r0 = rb * 24 + w * 6;
    const float* mp[6];
    #pragma unroll
    for (int r = 0; r < 6; ++r) mp[r] = p.L1 + (size_t)(r0 + r) * NED;
    float ua[6] = {0,0,0,0,0,0}, sa[6] = {0,0,0,0,0,0};
    float4 a[6], an[6];
    #pragma unroll
    for (int r = 0; r < 6; ++r) a[r] = ntload4(mp[r] + lane * 4);
    float4 z = ld4(Z0 + lane * 4), zn;
    for (int kb = 0; kb < NED; kb += 256) {
      const int k = kb + lane * 4;
      const bool more = (kb + 256) < NED;
      if (more) {
        #pragma unroll
        for (int r = 0; r < 6; ++r) an[r] = ntload4(mp[r] + k + 256);
        zn = ld4(Z0 + k + 256);
      }
      #pragma unroll
      for (int r = 0; r < 6; ++r) {
        ua[r] += a[r].x*z.x + a[r].y*z.y + a[r].z*z.z + a[r].w*z.w;
        sa[r] += a[r].x + a[r].y + a[r].z + a[r].w;
      }
      if (more) {
        #pragma unroll
        for (int r = 0; r < 6; ++r) a[r] = an[r];
        z = zn;
      }
    }
    #pragma unroll
    for (int r = 0; r < 6; ++r)
      #pragma unroll
      for (int m = 1; m < 64; m <<= 1) {
        ua[r] += __shfl_xor(ua[r], m, 64);
        sa[r] += __shfl_xor(sa[r], m, 64);
      }
    if (lane == 0) {
      float s1 = 0.f, s2 = 0.f, s3 = 0.f, s4 = 0.f, s5 = 0.f;
      #pragma unroll
      for (int r = 0; r < 6; ++r) {
        u[r0 + r] = ua[r]; s[r0 + r] = sa[r];
        s1 += ua[r]; s2 += sa[r];
        s3 += ua[r] * ua[r]; s4 += sa[r] * sa[r]; s5 += ua[r] * sa[r];
      }
      red[w * 5 + 0] = s1; red[w * 5 + 1] = s2; red[w * 5 + 2] = s3;
      red[w * 5 + 3] = s4; red[w * 5 + 4] = s5;
    }
    __syncthreads();
    if (tid < 5)
      atomicAdd(st + 32 + tid, red[tid] + red[5 + tid] + red[10 + tid] + red[15 + tid]);
  }
  if constexpr (ALL) cg::this_grid().sync();

  // ---- P8: Z1 from (u,s) via collapsed BN ----
  if constexpr (ALL || PHASE == 8) {
    if (gtid < NED) {
      const int e = gtid;
      const float invE = 1.f / (float)NED;
      const float Su = st[32], Ss = st[33], Suu = st[34], Sss = st[35], Sus = st[36];
      const float uu = u[e], ssv = s[e];
      float best = -3.4e38f;
      #pragma unroll
      for (int c = 0; c < 16; ++c) {
        const float wc = p.tW1[c], bc = p.tb1[c];
        const float mean = (wc * Su + bc * Ss) * invE;
        const float ex2 = (wc * wc * Suu + 2.f * wc * bc * Sus + bc * bc * Sss) * invE;
        const float var = ex2 - mean * mean;
        const float sc = p.bng1[c] * rsqrtf(var + EPS_BN);
        const float sh = p.bnb1[c] - mean * sc;
        best = fmaxf(best, fmaf(wc * uu + bc * ssv, sc, sh));
      }
      Z1[e] = fmaxf(best, 0.f);
    }
  }
  if constexpr (ALL) cg::this_grid().sync();

  // ---- P9: he = B1 @ [Z0 Z1]. 12 rows/block, 3 rows/wave. ----
  if constexpr (ALL || PHASE == 9) {
    const int r0 = blk * 12 + w * 3;
    const float* mp[3];
    #pragma unroll
    for (int r = 0; r < 3; ++r) mp[r] = p.B1 + (size_t)(r0 + r) * NED;
    float uu[3] = {0,0,0}, vv[3] = {0,0,0};
    float4 a[3], an[3];
    #pragma unroll
    for (int r = 0; r < 3; ++r) a[r] = ntload4(mp[r] + lane * 4);
    float4 z = ld4(Z0 + lane * 4), y = ld4(Z1 + lane * 4), zn, yn;
    for (int kb = 0; kb < NED; kb += 256) {
      const int k = kb + lane * 4;
      const bool more = (kb + 256) < NED;
      if (more) {
        #pragma unroll
        for (int r = 0; r < 3; ++r) an[r] = ntload4(mp[r] + k + 256);
        zn = ld4(Z0 + k + 256); yn = ld4(Z1 + k + 256);
      }
      #pragma unroll
      for (int r = 0; r < 3; ++r) {
        uu[r] += a[r].x*z.x + a[r].y*z.y + a[r].z*z.z + a[r].w*z.w;
        vv[r] += a[r].x*y.x + a[r].y*y.y + a[r].z*y.z + a[r].w*y.w;
      }
      if (more) {
        #pragma unroll
        for (int r = 0; r < 3; ++r) a[r] = an[r];
        z = zn; y = yn;
      }
    }
    #pragma unroll
    for (int r = 0; r < 3; ++r)
      #pragma unroll
      for (int m = 1; m < 64; m <<= 1) {
        uu[r] += __shfl_xor(uu[r], m, 64);
        vv[r] += __shfl_xor(vv[r], m, 64);
      }
    if (lane == 0) {
      #pragma unroll
      for (int r = 0; r < 3; ++r) {
        he[(r0 + r) * 2]     = uu[r];
        he[(r0 + r) * 2 + 1] = vv[r];
      }
    }
  }
  if constexpr (ALL) cg::this_grid().sync();

  // ---- P10: head partials. blk -> (nb=blk&7, jb=blk>>3); 64 chunks x 192 j. ----
  if constexpr (ALL || PHASE == 10) {
    const int nb = blk & 7, jb = blk >> 3;
    int n[3];
    float h[3][34];
    float acc[3] = {0.f, 0.f, 0.f};
    #pragma unroll
    for (int i = 0; i < 3; ++i) {
      n[i] = nb * 768 + i * 256 + tid;
      #pragma unroll
      for (int k = 0; k < 32; k += 4) {
        float4 v = ld4(Hn + (size_t)n[i] * 32 + k);
        h[i][k] = v.x; h[i][k+1] = v.y; h[i][k+2] = v.z; h[i][k+3] = v.w;
      }
      float2 e2 = *reinterpret_cast<const float2*>(he + n[i] * 2);
      h[i][32] = e2.x; h[i][33] = e2.y;
    }
    const int j0 = jb * 192;
    for (int j = j0; j < j0 + 192; ++j) {
      const float* wp = p.fc1W + (size_t)j * 34;
      const float bj = p.fc1b[j], vj = p.fc2W[j];
      float s0 = bj, s1 = bj, s2 = bj;
      #pragma unroll
      for (int k = 0; k < 34; ++k) {
        const float wk = wp[k];
        s0 = fmaf(h[0][k], wk, s0);
        s1 = fmaf(h[1][k], wk, s1);
        s2 = fmaf(h[2][k], wk, s2);
      }
      acc[0] += fmaxf(s0, 0.f) * vj;
      acc[1] += fmaxf(s1, 0.f) * vj;
      acc[2] += fmaxf(s2, 0.f) * vj;
    }
    #pragma unroll
    for (int i = 0; i < 3; ++i) pp[(size_t)jb * NND + n[i]] = acc[i];
  }
  if constexpr (ALL) cg::this_grid().sync();

  // ---- P11: final reduce + sigmoid ----
  if constexpr (ALL || PHASE == 11) {
    if (gtid < NND) {
      float acc = 0.f;
      for (int j = 0; j < 64; ++j) acc += pp[(size_t)j * NND + gtid];
      p.out[gtid] = 1.f / (1.f + expf(-(acc + p.fc2b[0])));
    }
  }
}

extern "C" void kernel_launch(void* const* d_in, const int* in_sizes, int n_in,
                              void* d_out, int out_size, void* d_ws, size_t ws_size,
                              hipStream_t stream) {
  Params p;
  p.X_n  = (const float*)d_in[0];
  p.X_e  = (const float*)d_in[1];
  p.A    = (const float*)d_in[2];
  p.L1   = (const float*)d_in[3];
  p.B1   = (const float*)d_in[4];
  p.gW0  = (const float*)d_in[5];
  p.gb0  = (const float*)d_in[6];
  p.gW1  = (const float*)d_in[7];
  p.gb1  = (const float*)d_in[8];
  p.tW0  = (const float*)d_in[9];
  p.tb0  = (const float*)d_in[10];
  p.bng0 = (const float*)d_in[11];
  p.bnb0 = (const float*)d_in[12];
  p.tW1  = (const float*)d_in[13];
  p.tb1  = (const float*)d_in[14];
  p.bng1 = (const float*)d_in[15];
  p.bnb1 = (const float*)d_in[16];
  p.fc1W = (const float*)d_in[17];
  p.fc1b = (const float*)d_in[18];
  p.fc2W = (const float*)d_in[19];
  p.fc2b = (const float*)d_in[20];
  p.ws   = (float*)d_ws;
  p.out  = (float*)d_out;

  // Host-side occupancy check (deterministic, capture-safe): cooperative only
  // if 512 blocks are guaranteed co-resident.
  int maxBlk = 0;
  hipError_t oe = hipOccupancyMaxActiveBlocksPerMultiprocessor(
      &maxBlk, pipeline<0>, 256, 0);
  bool coop_ok = (oe == hipSuccess) && (maxBlk >= 2);

  if (coop_ok) {
    void* kargs[] = { &p };
    hipError_t le = hipLaunchCooperativeKernel(
        (const void*)&pipeline<0>, dim3(GRID), dim3(256), kargs, 0, stream);
    if (le == hipSuccess) return;
  }

  // Fallback: identical phases as separate kernels.
  pipeline<1><<<GRID, 256, 0, stream>>>(p);
  pipeline<2><<<GRID, 256, 0, stream>>>(p);
  pipeline<3><<<GRID, 256, 0, stream>>>(p);
  pipeline<4><<<GRID, 256, 0, stream>>>(p);
  pipeline<5><<<GRID, 256, 0, stream>>>(p);
  pipeline<6><<<GRID, 256, 0, stream>>>(p);
  pipeline<7><<<GRID, 256, 0, stream>>>(p);
  pipeline<8><<<GRID, 256, 0, stream>>>(p);
  pipeline<9><<<GRID, 256, 0, stream>>>(p);
  pipeline<10><<<GRID, 256, 0, stream>>>(p);
  pipeline<11><<<GRID, 256, 0, stream>>>(p);
}

// Round 11
// 578.303 us; speedup vs baseline: 1.5194x; 1.0554x over previous
//
#include <hip/hip_runtime.h>
#include <hip/hip_cooperative_groups.h>
#include <math.h>

namespace cg = cooperative_groups;

#define NND 6144
#define NED 12288
#define GRID 1024
static constexpr float EPS_BN = 1e-5f;

// ---------------- ws layout (float offsets) ----------------
#define HN_OFF    0         // Hn [N,32]
#define HE_OFF    196608    // he [N,2]
#define ST_OFF    208896    // [64]: sum0[16] sq0[16] | us5[5]
#define Y_OFF     208960    // YT [32,N]
#define T0_OFF    405568    // H [N,32] / Zc0 [E,16]
#define T1_OFF    602176    // ZtT [16,E]
#define Z0_OFF    798784    // [E]
#define Z1_OFF    811072    // [E]
#define U_OFF     823360    // [E]
#define S_OFF     835648    // [E]
#define PP_OFF    847936    // head partials [128][N]

typedef float floatx4 __attribute__((ext_vector_type(4)));

__device__ __forceinline__ float4 ntload4(const float* p) {
  floatx4 v = __builtin_nontemporal_load(reinterpret_cast<const floatx4*>(p));
  return make_float4(v.x, v.y, v.z, v.w);
}
__device__ __forceinline__ float4 ld4(const float* p) {
  return *reinterpret_cast<const float4*>(p);
}
__device__ __forceinline__ void gll16(const float* g, float* l) {
  __builtin_amdgcn_global_load_lds(
      (const __attribute__((address_space(1))) unsigned int*)g,
      (__attribute__((address_space(3))) unsigned int*)l, 16, 0, 0);
}

struct Params {
  const float *X_n, *X_e, *A, *L1, *B1;
  const float *gW0, *gb0, *gW1, *gb1;
  const float *tW0, *tb0, *bng0, *bnb0;
  const float *tW1, *tb1, *bng1, *bnb1;
  const float *fc1W, *fc1b, *fc2W, *fc2b;
  float *ws;
  float *out;
};

// PHASE == 0: full pipeline with grid.sync (cooperative launch).
// PHASE == k (1..11): only phase k (fallback, one kernel per phase).
template<int PHASE>
__global__ __launch_bounds__(256, 4) void pipeline(Params p) {
  __shared__ float lds[10240];              // 40 KB pool -> 4 blocks/CU
  float* sst = &lds[10176];                 // 32-float scratch
  float* red = &lds[10208];                 // 20-float scratch

  const int tid  = threadIdx.x;
  const int lane = tid & 63;
  const int w    = tid >> 6;
  const int blk  = blockIdx.x;
  const int gtid = blk * 256 + tid;
  constexpr bool ALL = (PHASE == 0);

  float* Hn = p.ws + HN_OFF;
  float* he = p.ws + HE_OFF;
  float* st = p.ws + ST_OFF;
  float* Y  = p.ws + Y_OFF;
  float* T0 = p.ws + T0_OFF;
  float* T1 = p.ws + T1_OFF;
  float* Z0 = p.ws + Z0_OFF;
  float* Z1 = p.ws + Z1_OFF;
  float* u  = p.ws + U_OFF;
  float* s  = p.ws + S_OFF;
  float* pp = p.ws + PP_OFF;

  // gemm32: out = relu(A@Y^T + b). 6 rows/block; wave = 3 rows x 16 cols.
  // LDS: Y 32x256 (lds[0..8191]) + A 6x256 (lds[8192..9727]).
  auto gemm32 = [&](const float* bias, float* outp) {
    const int rg = w >> 1, cg_ = w & 1;
    const int r0 = blk * 6;
    const int c0 = cg_ * 16;
    float acc[3][16];
    #pragma unroll
    for (int r = 0; r < 3; ++r)
      #pragma unroll
      for (int c = 0; c < 16; ++c) acc[r][c] = 0.f;

    for (int kb = 0; kb < NND; kb += 256) {
      #pragma unroll
      for (int i = 0; i < 8; ++i) {
        const int yr = w * 8 + i;
        gll16(Y + (size_t)yr * NND + kb + lane * 4, &lds[yr * 256]);
      }
      #pragma unroll
      for (int i = 0; i < 2; ++i) {
        const int ar = w * 2 + i;
        if (ar < 6)
          gll16(p.A + (size_t)(r0 + ar) * NND + kb + lane * 4, &lds[8192 + ar * 256]);
      }
      __syncthreads();
      float4 av[3];
      #pragma unroll
      for (int r = 0; r < 3; ++r)
        av[r] = ld4(&lds[8192 + (rg * 3 + r) * 256 + lane * 4]);
      #pragma unroll
      for (int c = 0; c < 16; ++c) {
        const float4 y = ld4(&lds[(c0 + c) * 256 + lane * 4]);
        #pragma unroll
        for (int r = 0; r < 3; ++r) {
          acc[r][c] = fmaf(av[r].x, y.x, acc[r][c]);
          acc[r][c] = fmaf(av[r].y, y.y, acc[r][c]);
          acc[r][c] = fmaf(av[r].z, y.z, acc[r][c]);
          acc[r][c] = fmaf(av[r].w, y.w, acc[r][c]);
        }
      }
      __syncthreads();
    }
    // per-row: fold bits 5,4 then compact 16 values over bits 3..0
    #pragma unroll
    for (int r = 0; r < 3; ++r) {
      float wv[16];
      #pragma unroll
      for (int c = 0; c < 16; ++c) {
        float t = acc[r][c] + __shfl_xor(acc[r][c], 32, 64);
        wv[c] = t + __shfl_xor(t, 16, 64);
      }
      #pragma unroll
      for (int b = 3; b >= 0; --b) {
        const int m = 1 << b;
        const bool hi = (lane & m) != 0;
        #pragma unroll
        for (int i = 0; i < (1 << b); ++i) {
          float x = wv[i], yv = wv[i + (1 << b)];
          float send = hi ? x : yv;
          float recv = __shfl_xor(send, m, 64);
          wv[i] = (hi ? yv : x) + recv;
        }
      }
      if (lane < 16) {
        float v = fmaxf(wv[0] + bias[c0 + lane], 0.f);
        outp[(size_t)(r0 + rg * 3 + r) * 32 + c0 + lane] = v;
      }
    }
  };

  // ---- P1: zero stats; Y0T = X_n@gW0^T; ZtT = X_e@tW0^T + tb0 ----
  if constexpr (ALL || PHASE == 1) {
    if (blk == 0 && tid < 64) st[tid] = 0.f;
    if (gtid < NND) {
      const int m = gtid;
      float x[32];
      #pragma unroll
      for (int k = 0; k < 32; k += 4) {
        float4 v = ld4(p.X_n + (size_t)m * 32 + k);
        x[k] = v.x; x[k+1] = v.y; x[k+2] = v.z; x[k+3] = v.w;
      }
      #pragma unroll
      for (int oc = 0; oc < 32; ++oc) {
        float acc = 0.f;
        #pragma unroll
        for (int k = 0; k < 32; ++k) acc = fmaf(x[k], p.gW0[oc * 32 + k], acc);
        Y[(size_t)oc * NND + m] = acc;
      }
    } else if (gtid < NND + NED) {
      const int e = gtid - NND;
      float x[16];
      #pragma unroll
      for (int k = 0; k < 16; k += 4) {
        float4 v = ld4(p.X_e + (size_t)e * 16 + k);
        x[k] = v.x; x[k+1] = v.y; x[k+2] = v.z; x[k+3] = v.w;
      }
      #pragma unroll
      for (int oc = 0; oc < 16; ++oc) {
        float acc = p.tb0[oc];
        #pragma unroll
        for (int k = 0; k < 16; ++k) acc = fmaf(x[k], p.tW0[oc * 16 + k], acc);
        T1[(size_t)oc * NED + e] = acc;
      }
    }
  }
  if constexpr (ALL) cg::this_grid().sync();

  // ---- P2: H(T0) = relu(A@Y0 + gb0) ----
  if constexpr (ALL || PHASE == 2) gemm32(p.gb0, T0);
  if constexpr (ALL) cg::this_grid().sync();

  // ---- P3: Y1T = H@gW1^T ----
  if constexpr (ALL || PHASE == 3) {
    if (gtid < NND) {
      const int m = gtid;
      float x[32];
      #pragma unroll
      for (int k = 0; k < 32; k += 4) {
        float4 v = ld4(T0 + (size_t)m * 32 + k);
        x[k] = v.x; x[k+1] = v.y; x[k+2] = v.z; x[k+3] = v.w;
      }
      #pragma unroll
      for (int oc = 0; oc < 32; ++oc) {
        float acc = 0.f;
        #pragma unroll
        for (int k = 0; k < 32; ++k) acc = fmaf(x[k], p.gW1[oc * 32 + k], acc);
        Y[(size_t)oc * NND + m] = acc;
      }
    }
  }
  if constexpr (ALL) cg::this_grid().sync();

  // ---- P4: Hn = relu(A@Y1 + gb1) ----
  if constexpr (ALL || PHASE == 4) gemm32(p.gb1, Hn);
  if constexpr (ALL) cg::this_grid().sync();

  // ---- P5: Zc0(T0) = L1@ZtT^T + fused BN stats ----
  // 12 rows/block; wave = 3 rows x 16 cols.
  // LDS: Zt 16x256 (lds[0..4095]) + L1 12x256 (lds[4096..7167]).
  if constexpr (ALL || PHASE == 5) {
    const int r0 = blk * 12;
    float acc[3][16];
    #pragma unroll
    for (int r = 0; r < 3; ++r)
      #pragma unroll
      for (int c = 0; c < 16; ++c) acc[r][c] = 0.f;

    for (int kb = 0; kb < NED; kb += 256) {
      #pragma unroll
      for (int i = 0; i < 4; ++i) {
        const int yr = w * 4 + i;
        gll16(T1 + (size_t)yr * NED + kb + lane * 4, &lds[yr * 256]);
      }
      #pragma unroll
      for (int i = 0; i < 3; ++i) {
        const int ar = w * 3 + i;
        gll16(p.L1 + (size_t)(r0 + ar) * NED + kb + lane * 4, &lds[4096 + ar * 256]);
      }
      __syncthreads();
      float4 av[3];
      #pragma unroll
      for (int r = 0; r < 3; ++r)
        av[r] = ld4(&lds[4096 + (w * 3 + r) * 256 + lane * 4]);
      #pragma unroll
      for (int c = 0; c < 16; ++c) {
        const float4 y = ld4(&lds[c * 256 + lane * 4]);
        #pragma unroll
        for (int r = 0; r < 3; ++r) {
          acc[r][c] = fmaf(av[r].x, y.x, acc[r][c]);
          acc[r][c] = fmaf(av[r].y, y.y, acc[r][c]);
          acc[r][c] = fmaf(av[r].z, y.z, acc[r][c]);
          acc[r][c] = fmaf(av[r].w, y.w, acc[r][c]);
        }
      }
      __syncthreads();
    }
    float stS = 0.f, stQ = 0.f;
    #pragma unroll
    for (int r = 0; r < 3; ++r) {
      float wv[16];
      #pragma unroll
      for (int c = 0; c < 16; ++c) {
        float t = acc[r][c] + __shfl_xor(acc[r][c], 32, 64);
        wv[c] = t + __shfl_xor(t, 16, 64);
      }
      #pragma unroll
      for (int b = 3; b >= 0; --b) {
        const int m = 1 << b;
        const bool hi = (lane & m) != 0;
        #pragma unroll
        for (int i = 0; i < (1 << b); ++i) {
          float x = wv[i], yv = wv[i + (1 << b)];
          float send = hi ? x : yv;
          float recv = __shfl_xor(send, m, 64);
          wv[i] = (hi ? yv : x) + recv;
        }
      }
      if (lane < 16) {
        const float v = wv[0];
        T0[(size_t)(r0 + w * 3 + r) * 16 + lane] = v;
        stS += v; stQ += v * v;
      }
    }
    if (tid < 32) sst[tid] = 0.f;
    __syncthreads();
    if (lane < 16) {
      atomicAdd(&sst[lane], stS);
      atomicAdd(&sst[16 + lane], stQ);
    }
    __syncthreads();
    if (tid < 32) atomicAdd(st + tid, sst[tid]);
  }
  if constexpr (ALL) cg::this_grid().sync();

  // ---- P6: Z0 = relu(max_c BN(Zc0)) ----
  if constexpr (ALL || PHASE == 6) {
    if (gtid < NED) {
      const int e = gtid;
      const float invE = 1.f / (float)NED;
      float best = -3.4e38f;
      #pragma unroll
      for (int c = 0; c < 16; ++c) {
        float m = st[c] * invE;
        float var = st[16 + c] * invE - m * m;
        float sc = p.bng0[c] * rsqrtf(var + EPS_BN);
        float sh = p.bnb0[c] - m * sc;
        best = fmaxf(best, fmaf(T0[(size_t)e * 16 + c], sc, sh));
      }
      Z0[e] = fmaxf(best, 0.f);
    }
  }
  if constexpr (ALL) cg::this_grid().sync();

  // ---- P7: u = L1@Z0, s = L1@1, fused st5. REV order (L3 tail reuse). ----
  // 12 rows/block, 3 rows/wave, depth-1 prefetch.
  if constexpr (ALL || PHASE == 7) {
    const int rb = GRID - 1 - blk;
    const int r0 = rb * 12 + w * 3;
    const float* mp[3];
    #pragma unroll
    for (int r = 0; r < 3; ++r) mp[r] = p.L1 + (size_t)(r0 + r) * NED;
    float ua[3] = {0,0,0}, sa[3] = {0,0,0};
    float4 a[3], an[3];
    #pragma unroll
    for (int r = 0; r < 3; ++r) a[r] = ntload4(mp[r] + lane * 4);
    float4 z = ld4(Z0 + lane * 4), zn;
    for (int kb = 0; kb < NED; kb += 256) {
      const int k = kb + lane * 4;
      const bool more = (kb + 256) < NED;
      if (more) {
        #pragma unroll
        for (int r = 0; r < 3; ++r) an[r] = ntload4(mp[r] + k + 256);
        zn = ld4(Z0 + k + 256);
      }
      #pragma unroll
      for (int r = 0; r < 3; ++r) {
        ua[r] += a[r].x*z.x + a[r].y*z.y + a[r].z*z.z + a[r].w*z.w;
        sa[r] += a[r].x + a[r].y + a[r].z + a[r].w;
      }
      if (more) {
        #pragma unroll
        for (int r = 0; r < 3; ++r) a[r] = an[r];
        z = zn;
      }
    }
    #pragma unroll
    for (int r = 0; r < 3; ++r)
      #pragma unroll
      for (int m = 1; m < 64; m <<= 1) {
        ua[r] += __shfl_xor(ua[r], m, 64);
        sa[r] += __shfl_xor(sa[r], m, 64);
      }
    if (lane == 0) {
      float s1 = 0.f, s2 = 0.f, s3 = 0.f, s4 = 0.f, s5 = 0.f;
      #pragma unroll
      for (int r = 0; r < 3; ++r) {
        u[r0 + r] = ua[r]; s[r0 + r] = sa[r];
        s1 += ua[r]; s2 += sa[r];
        s3 += ua[r] * ua[r]; s4 += sa[r] * sa[r]; s5 += ua[r] * sa[r];
      }
      red[w * 5 + 0] = s1; red[w * 5 + 1] = s2; red[w * 5 + 2] = s3;
      red[w * 5 + 3] = s4; red[w * 5 + 4] = s5;
    }
    __syncthreads();
    if (tid < 5)
      atomicAdd(st + 32 + tid, red[tid] + red[5 + tid] + red[10 + tid] + red[15 + tid]);
  }
  if constexpr (ALL) cg::this_grid().sync();

  // ---- P8: Z1 from (u,s) via collapsed BN ----
  if constexpr (ALL || PHASE == 8) {
    if (gtid < NED) {
      const int e = gtid;
      const float invE = 1.f / (float)NED;
      const float Su = st[32], Ss = st[33], Suu = st[34], Sss = st[35], Sus = st[36];
      const float uu = u[e], ssv = s[e];
      float best = -3.4e38f;
      #pragma unroll
      for (int c = 0; c < 16; ++c) {
        const float wc = p.tW1[c], bc = p.tb1[c];
        const float mean = (wc * Su + bc * Ss) * invE;
        const float ex2 = (wc * wc * Suu + 2.f * wc * bc * Sus + bc * bc * Sss) * invE;
        const float var = ex2 - mean * mean;
        const float sc = p.bng1[c] * rsqrtf(var + EPS_BN);
        const float sh = p.bnb1[c] - mean * sc;
        best = fmaxf(best, fmaf(wc * uu + bc * ssv, sc, sh));
      }
      Z1[e] = fmaxf(best, 0.f);
    }
  }
  if constexpr (ALL) cg::this_grid().sync();

  // ---- P9: he = B1 @ [Z0 Z1]. 12 rows/block, 3 rows/wave. ----
  if constexpr (ALL || PHASE == 9) {
    const int r0 = blk * 12 + w * 3;
    if (r0 < NND) {
      const float* mp[3];
      #pragma unroll
      for (int r = 0; r < 3; ++r) mp[r] = p.B1 + (size_t)(r0 + r) * NED;
      float uu[3] = {0,0,0}, vv[3] = {0,0,0};
      float4 a[3], an[3];
      #pragma unroll
      for (int r = 0; r < 3; ++r) a[r] = ntload4(mp[r] + lane * 4);
      float4 z = ld4(Z0 + lane * 4), y = ld4(Z1 + lane * 4), zn, yn;
      for (int kb = 0; kb < NED; kb += 256) {
        const int k = kb + lane * 4;
        const bool more = (kb + 256) < NED;
        if (more) {
          #pragma unroll
          for (int r = 0; r < 3; ++r) an[r] = ntload4(mp[r] + k + 256);
          zn = ld4(Z0 + k + 256); yn = ld4(Z1 + k + 256);
        }
        #pragma unroll
        for (int r = 0; r < 3; ++r) {
          uu[r] += a[r].x*z.x + a[r].y*z.y + a[r].z*z.z + a[r].w*z.w;
          vv[r] += a[r].x*y.x + a[r].y*y.y + a[r].z*y.z + a[r].w*y.w;
        }
        if (more) {
          #pragma unroll
          for (int r = 0; r < 3; ++r) a[r] = an[r];
          z = zn; y = yn;
        }
      }
      #pragma unroll
      for (int r = 0; r < 3; ++r)
        #pragma unroll
        for (int m = 1; m < 64; m <<= 1) {
          uu[r] += __shfl_xor(uu[r], m, 64);
          vv[r] += __shfl_xor(vv[r], m, 64);
        }
      if (lane == 0) {
        #pragma unroll
        for (int r = 0; r < 3; ++r) {
          he[(r0 + r) * 2]     = uu[r];
          he[(r0 + r) * 2 + 1] = vv[r];
        }
      }
    }
  }
  if constexpr (ALL) cg::this_grid().sync();

  // ---- P10: head partials. blk -> (nb=blk&7, jb=blk>>3); 128 chunks x 96 j. ----
  if constexpr (ALL || PHASE == 10) {
    const int nb = blk & 7, jb = blk >> 3;
    int n[3];
    float h[3][34];
    float acc[3] = {0.f, 0.f, 0.f};
    #pragma unroll
    for (int i = 0; i < 3; ++i) {
      n[i] = nb * 768 + i * 256 + tid;
      #pragma unroll
      for (int k = 0; k < 32; k += 4) {
        float4 v = ld4(Hn + (size_t)n[i] * 32 + k);
        h[i][k] = v.x; h[i][k+1] = v.y; h[i][k+2] = v.z; h[i][k+3] = v.w;
      }
      float2 e2 = *reinterpret_cast<const float2*>(he + n[i] * 2);
      h[i][32] = e2.x; h[i][33] = e2.y;
    }
    const int j0 = jb * 96;
    for (int j = j0; j < j0 + 96; ++j) {
      const float* wp = p.fc1W + (size_t)j * 34;
      const float bj = p.fc1b[j], vj = p.fc2W[j];
      float s0 = bj, s1 = bj, s2 = bj;
      #pragma unroll
      for (int k = 0; k < 34; ++k) {
        const float wk = wp[k];
        s0 = fmaf(h[0][k], wk, s0);
        s1 = fmaf(h[1][k], wk, s1);
        s2 = fmaf(h[2][k], wk, s2);
      }
      acc[0] += fmaxf(s0, 0.f) * vj;
      acc[1] += fmaxf(s1, 0.f) * vj;
      acc[2] += fmaxf(s2, 0.f) * vj;
    }
    #pragma unroll
    for (int i = 0; i < 3; ++i) pp[(size_t)jb * NND + n[i]] = acc[i];
  }
  if constexpr (ALL) cg::this_grid().sync();

  // ---- P11: final reduce + sigmoid ----
  if constexpr (ALL || PHASE == 11) {
    if (gtid < NND) {
      float acc = 0.f;
      for (int j = 0; j < 128; ++j) acc += pp[(size_t)j * NND + gtid];
      p.out[gtid] = 1.f / (1.f + expf(-(acc + p.fc2b[0])));
    }
  }
}

extern "C" void kernel_launch(void* const* d_in, const int* in_sizes, int n_in,
                              void* d_out, int out_size, void* d_ws, size_t ws_size,
                              hipStream_t stream) {
  Params p;
  p.X_n  = (const float*)d_in[0];
  p.X_e  = (const float*)d_in[1];
  p.A    = (const float*)d_in[2];
  p.L1   = (const float*)d_in[3];
  p.B1   = (const float*)d_in[4];
  p.gW0  = (const float*)d_in[5];
  p.gb0  = (const float*)d_in[6];
  p.gW1  = (const float*)d_in[7];
  p.gb1  = (const float*)d_in[8];
  p.tW0  = (const float*)d_in[9];
  p.tb0  = (const float*)d_in[10];
  p.bng0 = (const float*)d_in[11];
  p.bnb0 = (const float*)d_in[12];
  p.tW1  = (const float*)d_in[13];
  p.tb1  = (const float*)d_in[14];
  p.bng1 = (const float*)d_in[15];
  p.bnb1 = (const float*)d_in[16];
  p.fc1W = (const float*)d_in[17];
  p.fc1b = (const float*)d_in[18];
  p.fc2W = (const float*)d_in[19];
  p.fc2b = (const float*)d_in[20];
  p.ws   = (float*)d_ws;
  p.out  = (float*)d_out;

  // Cooperative only if 1024 blocks are guaranteed co-resident (4/CU x 256 CU).
  int maxBlk = 0;
  hipError_t oe = hipOccupancyMaxActiveBlocksPerMultiprocessor(
      &maxBlk, pipeline<0>, 256, 0);
  bool coop_ok = (oe == hipSuccess) && (maxBlk >= 4);

  if (coop_ok) {
    void* kargs[] = { &p };
    hipError_t le = hipLaunchCooperativeKernel(
        (const void*)&pipeline<0>, dim3(GRID), dim3(256), kargs, 0, stream);
    if (le == hipSuccess) return;
  }

  // Fallback: identical phases as separate kernels.
  pipeline<1><<<GRID, 256, 0, stream>>>(p);
  pipeline<2><<<GRID, 256, 0, stream>>>(p);
  pipeline<3><<<GRID, 256, 0, stream>>>(p);
  pipeline<4><<<GRID, 256, 0, stream>>>(p);
  pipeline<5><<<GRID, 256, 0, stream>>>(p);
  pipeline<6><<<GRID, 256, 0, stream>>>(p);
  pipeline<7><<<GRID, 256, 0, stream>>>(p);
  pipeline<8><<<GRID, 256, 0, stream>>>(p);
  pipeline<9><<<GRID, 256, 0, stream>>>(p);
  pipeline<10><<<GRID, 256, 0, stream>>>(p);
  pipeline<11><<<GRID, 256, 0, stream>>>(p);
}